// Round 5
// baseline (273.199 us; speedup 1.0000x reference)
//
#include <hip/hip_runtime.h>
#include <hip/hip_fp16.h>

// ============ R5: INSTRUMENTATION ROUND ============
// Identical structure to R4, but passA / passB1G / interp_tiled repeat their
// body REP=3 times (idempotent) so true per-kernel duration (= shown/3) and
// counters become visible above the ~44us harness fillBuffer rows in top-5.
#define REP 3

#define GSZ 640
#define NIMG 320
#define MS 102400
#define NC 12
#define BETA_F 13.8551004f
#define TWOPI_F 6.2831855f
#define GSC 16777216.0f
#define GSC_INV 5.9604645e-8f

#define TEDGE 16
#define NT1 40
#define NTILES 1600
#define PAT 21
#define PROW 252
#define GPAD 645
#define NSMAX 128

// ---------- Bessel I0 ----------
__device__ __forceinline__ float i0f(float x) {
    float ax = fabsf(x);
    if (ax < 3.75f) {
        float t = ax * (1.0f / 3.75f);
        t *= t;
        return 1.0f + t * (3.5156229f + t * (3.0899424f + t * (1.2067492f +
                     t * (0.2659732f + t * (0.0360768f + t * 0.0045813f)))));
    } else {
        float t = 3.75f / ax;
        float p = 0.39894228f + t * (0.01328592f + t * (0.00225319f + t * (-0.00157565f +
                  t * (0.00916281f + t * (-0.02057706f + t * (0.02635537f +
                  t * (-0.01647633f + t * 0.00392377f)))))));
        return p * __expf(ax) * rsqrtf(ax);
    }
}

__device__ __forceinline__ float kbval(float u) {
    float mm = fabsf(u) * (1.0f / 3.0f);
    float s = 1.0f - mm * mm;
    s = s > 0.0f ? s : 0.0f;
    float v = i0f(BETA_F * sqrtf(s)) * (1.0f / 6.0f);
    return (mm <= 1.0f) ? v : 0.0f;
}

__device__ __forceinline__ int tapbase(float om, float* frac) {
    float t = fmodf((om * 640.0f) / TWOPI_F, 640.0f);
    if (t < 0.0f) t += 640.0f;
    float b = floorf(t);
    *frac = t - b;
    int ib = (int)b;
    if (ib >= GSZ) ib -= GSZ;
    return ib;
}

__device__ __forceinline__ float2 cmul(float2 a, float2 w) {
    return make_float2(a.x * w.x - a.y * w.y, a.x * w.y + a.y * w.x);
}

// ===== wave-level 640-pt FFT (as R4) =====
__device__ __forceinline__ void wf_init(int lane, float2* t64, float2* t640, int* br) {
    #pragma unroll
    for (int m = 0; m < 6; ++m) {
        int mask = 32 >> m;
        float e = (float)((lane & (mask - 1)) << m);
        float sn, cs;
        __sincosf((-TWOPI_F / 64.0f) * e, &sn, &cs);
        t64[m] = make_float2(cs, sn);
    }
    float sn, cs;
    __sincosf((-TWOPI_F / 640.0f) * (float)lane, &sn, &cs);
    float2 w1 = make_float2(cs, sn);
    t640[0] = make_float2(1.0f, 0.0f);
    #pragma unroll
    for (int k = 1; k < 10; ++k) t640[k] = cmul(t640[k - 1], w1);
    *br = (int)(__brev((unsigned int)lane) >> 26);
}

__device__ __forceinline__ void dft10(const float2* v, float2* y) {
    const float wr5[5] = {1.0f, 0.30901699f, -0.80901699f, -0.80901699f, 0.30901699f};
    const float wi5[5] = {0.0f, -0.95105652f, -0.58778525f, 0.58778525f, 0.95105652f};
    float2 E[5], O[5];
    #pragma unroll
    for (int r = 0; r < 5; ++r) {
        float er = v[0].x, ei = v[0].y;
        float os = v[1].x, oi = v[1].y;
        #pragma unroll
        for (int c = 1; c < 5; ++c) {
            int k = (r * c) % 5;
            er += v[2 * c].x * wr5[k] - v[2 * c].y * wi5[k];
            ei += v[2 * c].x * wi5[k] + v[2 * c].y * wr5[k];
            os += v[2 * c + 1].x * wr5[k] - v[2 * c + 1].y * wi5[k];
            oi += v[2 * c + 1].x * wi5[k] + v[2 * c + 1].y * wr5[k];
        }
        E[r] = make_float2(er, ei);
        O[r] = make_float2(os, oi);
    }
    const float wr10[10] = {1.0f, 0.80901699f, 0.30901699f, -0.30901699f, -0.80901699f,
                            -1.0f, -0.80901699f, -0.30901699f, 0.30901699f, 0.80901699f};
    const float wi10[10] = {0.0f, -0.58778525f, -0.95105652f, -0.95105652f, -0.58778525f,
                            0.0f, 0.58778525f, 0.95105652f, 0.95105652f, 0.58778525f};
    #pragma unroll
    for (int k = 0; k < 10; ++k) {
        int r = k % 5;
        float2 t = cmul(O[r], make_float2(wr10[k], wi10[k]));
        y[k] = make_float2(E[r].x + t.x, E[r].y + t.y);
    }
}

__device__ __forceinline__ void wfft640(float2* v, const float2* t640, const float2* t64,
                                        int lane) {
    float2 y[10];
    dft10(v, y);
    #pragma unroll
    for (int k = 1; k < 10; ++k) y[k] = cmul(y[k], t640[k]);
    #pragma unroll
    for (int m = 0; m < 6; ++m) {
        int mask = 32 >> m;
        bool up = (lane & mask) != 0;
        float2 tw = t64[m];
        #pragma unroll
        for (int k = 0; k < 10; ++k) {
            float2 a = y[k];
            float2 b;
            b.x = __shfl_xor(a.x, mask, 64);
            b.y = __shfl_xor(a.y, mask, 64);
            float2 d = make_float2(b.x - a.x, b.y - a.y);
            float2 cm = cmul(d, tw);
            y[k] = up ? cm : make_float2(a.x + b.x, a.y + b.y);
        }
    }
    #pragma unroll
    for (int k = 0; k < 10; ++k) v[k] = y[k];
}

// ---------- block-0 inline scan ----------
__device__ void scan_inline(const int* __restrict__ cnt, int* __restrict__ offs, int* sp) {
    int t = threadIdx.x;
    int c7[7];
    int psum = 0;
    if (t < 256) {
        #pragma unroll
        for (int k = 0; k < 7; ++k) {
            int i = t * 7 + k;
            int v = (i < NTILES) ? cnt[i] : 0;
            c7[k] = v;
            psum += v;
        }
        sp[t] = psum;
    }
    __syncthreads();
    for (int off = 1; off < 256; off <<= 1) {
        int v = (t >= off && t < 256) ? sp[t - off] : 0;
        __syncthreads();
        if (t < 256) sp[t] += v;
        __syncthreads();
    }
    if (t < 256) {
        int run = (t == 0) ? 0 : sp[t - 1];
        #pragma unroll
        for (int k = 0; k < 7; ++k) {
            int i = t * 7 + k;
            if (i < NTILES) offs[i] = run;
            run += c7[k];
        }
    }
}

// ---------- pass A (REP x) ----------
__global__ __launch_bounds__(512)
void passA_kernel(const float* __restrict__ img_r, const float* __restrict__ img_i,
                  const float* __restrict__ sm_r, const float* __restrict__ sm_i,
                  const float* __restrict__ kt, int* __restrict__ cnt,
                  unsigned int* __restrict__ R16) {
    __shared__ unsigned int Rs[8][GSZ];
    __shared__ float apodS[NIMG];
    int gid = blockIdx.x * 512 + threadIdx.x;
    if (gid < MS) {                              // once only (not idempotent)
        float f;
        int ibu = tapbase(kt[gid], &f);
        int ibq = tapbase(kt[MS + gid], &f);
        atomicAdd(&cnt[(ibq >> 4) * NT1 + (ibu >> 4)], 1);
    }
    if (threadIdx.x < NIMG) {
        int n = threadIdx.x;
        float s = 0.0f;
        #pragma unroll
        for (int j = -3; j <= 3; ++j)
            s += kbval((float)j) * __cosf((TWOPI_F * (float)j * ((float)n - 160.0f)) / 640.0f);
        apodS[n] = 1.0f / s;
    }
    int lane = threadIdx.x & 63;
    int wv = threadIdx.x >> 6;
    float2 t64[6], t640[10];
    int br;
    wf_init(lane, t64, t640, &br);
    __syncthreads();                             // apodS ready
    int id = blockIdx.x * 8 + wv;
    int c = id / 320, ri = id - 320 * c;
    int h = (ri < 160) ? ri + 160 : ri - 160;
    const float* ir = img_r + h * NIMG;
    const float* ii = img_i + h * NIMG;
    const float* smr = sm_r + (c * NIMG + h) * NIMG;
    const float* smi = sm_i + (c * NIMG + h) * NIMG;
    float ah = apodS[h] * (GSC / 640.0f);
    unsigned int* rs = Rs[wv];
    unsigned int* outp = R16 + (c * 320 + ri) * GSZ;
    for (int rep = 0; rep < REP; ++rep) {
        asm volatile("" ::: "memory");           // force true recompute per rep
        auto ld = [&](int wc) {
            float xr = ir[wc], xi = ii[wc];
            float sr = smr[wc], si = smi[wc];
            float sc = ah * apodS[wc];
            return make_float2((xr * sr - xi * si) * sc, (xr * si + xi * sr) * sc);
        };
        const float2 z2 = make_float2(0.0f, 0.0f);
        float2 v[10];
        v[0] = ld(lane + 160);
        v[1] = ld(lane + 224);
        { float2 tv = ld((lane < 32) ? lane + 288 : 0); v[2] = (lane < 32) ? tv : z2; }
        v[3] = z2; v[4] = z2; v[5] = z2; v[6] = z2;
        { float2 tv = ld((lane >= 32) ? lane - 32 : 0); v[7] = (lane >= 32) ? tv : z2; }
        v[8] = ld(lane + 32);
        v[9] = ld(lane + 96);
        wfft640(v, t640, t64, lane);
        #pragma unroll
        for (int k = 0; k < 10; ++k) {
            __half2 hv = __float22half2_rn(v[k]);
            rs[10 * br + k] = *(const unsigned int*)&hv;
        }
        #pragma unroll
        for (int j = 0; j < 10; ++j)
            outp[lane + 64 * j] = rs[lane + 64 * j];
    }
}

// ---------- pass B1G (REP x) ----------
__global__ __launch_bounds__(512)
void passB1G_kernel(const unsigned int* __restrict__ R16, const int* __restrict__ cnt,
                    int* __restrict__ offs, unsigned int* __restrict__ Gpad) {
    __shared__ unsigned int Gs[GSZ * 13];
    __shared__ int sp[256];
    if (blockIdx.x == 0) scan_inline(cnt, offs, sp);   // once only
    int lane = threadIdx.x & 63;
    int wv = threadIdx.x >> 6;
    float2 t64[6], t640[10];
    int br;
    wf_init(lane, t64, t640, &br);
    int q = ((int)blockIdx.x & 7) * 80 + ((int)blockIdx.x >> 3);
    const float2 z2 = make_float2(0.0f, 0.0f);
    for (int rep = 0; rep < REP; ++rep) {
        asm volatile("" ::: "memory");
        for (int c = wv; c < NC; c += 8) {
            const unsigned int* col = R16 + (size_t)c * 320 * GSZ + q;
            auto ld = [&](int t) {
                unsigned int raw = col[(size_t)t * GSZ];
                return __half22float2(*(const __half2*)&raw);
            };
            float2 v[10];
            v[0] = ld(lane);
            v[1] = ld(lane + 64);
            { float2 tv = ld(lane + 128);
              v[2] = (lane < 32) ? tv : z2;
              v[7] = (lane < 32) ? z2 : tv; }
            v[3] = z2; v[4] = z2; v[5] = z2; v[6] = z2;
            v[8] = ld(lane + 192);
            v[9] = ld(lane + 256);
            wfft640(v, t640, t64, lane);
            #pragma unroll
            for (int k = 0; k < 10; ++k) {
                __half2 hv = __float22half2_rn(v[k]);
                Gs[(10 * br + k) * 13 + c] = *(const unsigned int*)&hv;
            }
        }
        __syncthreads();                              // all 12 coils stashed
        size_t rowbase = (size_t)(q + 2) * (GPAD * 12);
        for (int idx = threadIdx.x; idx < GPAD * 12; idx += 512) {
            int up = idx / 12, cc = idx - up * 12;
            int u = (up < 2) ? up + 638 : ((up < 642) ? up - 2 : up - 642);
            Gpad[rowbase + idx] = Gs[u * 13 + cc];
        }
        int qp2 = (q < 3) ? q + 642 : ((q >= 638) ? q - 638 : -1);
        if (qp2 >= 0) {
            size_t rb2 = (size_t)qp2 * (GPAD * 12);
            for (int idx = threadIdx.x; idx < GPAD * 12; idx += 512) {
                int up = idx / 12, cc = idx - up * 12;
                int u = (up < 2) ? up + 638 : ((up < 642) ? up - 2 : up - 642);
                Gpad[rb2 + idx] = Gs[u * 13 + cc];
            }
        }
        __syncthreads();                              // before next rep's Gs overwrite
    }
}

// ---------- bin scatter (once; atomics not idempotent) ----------
__global__ __launch_bounds__(256)
void binscatter_kernel(const float* __restrict__ kt, int* __restrict__ offs,
                       int* __restrict__ order) {
    int m = blockIdx.x * 256 + threadIdx.x;
    float f;
    int ibu = tapbase(kt[m], &f);
    int ibq = tapbase(kt[MS + m], &f);
    int pos = atomicAdd(&offs[(ibq >> 4) * NT1 + (ibu >> 4)], 1);
    order[pos] = m;
}

// ---------- tiled interpolation (REP x) ----------
__global__ __launch_bounds__(256)
void interp_tiled_kernel(const float* __restrict__ kt,
                         const unsigned int* __restrict__ Gpad,
                         const int* __restrict__ cnt, const int* __restrict__ offs,
                         const int* __restrict__ order, float2* __restrict__ out) {
    __shared__ __align__(16) unsigned int patch[PAT * PROW];
    __shared__ float tw1s[NSMAX][6], tw2s[NSMAX][6];
    __shared__ int tslm[NSMAX];
    int tile = blockIdx.x;
    int TQ = tile / NT1, TU = tile - TQ * NT1;
    for (int rep = 0; rep < REP; ++rep) {
        asm volatile("" ::: "memory");
        {
            const uint4* g4 = (const uint4*)Gpad;
            uint4* p4 = (uint4*)patch;
            int base = (TQ * TEDGE * GPAD + TU * TEDGE) * 3;
            for (int i = threadIdx.x; i < PAT * 63; i += 256) {
                int r = i / 63, c = i - r * 63;
                p4[i] = g4[base + r * (GPAD * 3) + c];
            }
        }
        int end = offs[tile], ns = cnt[tile], start = end - ns;
        for (int s0 = 0; s0 < ns; s0 += NSMAX) {
            int nss = min(NSMAX, ns - s0);
            if ((int)threadIdx.x < nss) {
                int m = order[start + s0 + threadIdx.x];
                float fu, fq;
                int ibu = tapbase(kt[m], &fu);
                int ibq = tapbase(kt[MS + m], &fq);
                #pragma unroll
                for (int j = 0; j < 6; ++j) {
                    tw1s[threadIdx.x][j] = kbval(fu + (float)(2 - j));
                    tw2s[threadIdx.x][j] = kbval(fq + (float)(2 - j)) * GSC_INV;
                }
                tslm[threadIdx.x] = (m << 8) | ((ibu & 15) << 4) | (ibq & 15);
            }
            __syncthreads();
            for (int it = threadIdx.x; it < 3 * nss; it += 256) {
                int s = it / 3;
                int p = it - 3 * s;
                int pk = tslm[s];
                int slq = pk & 15, slu = (pk >> 4) & 15, m = pk >> 8;
                float ar[4] = {0.f, 0.f, 0.f, 0.f}, ai[4] = {0.f, 0.f, 0.f, 0.f};
                #pragma unroll
                for (int j2 = 0; j2 < 6; ++j2) {
                    int rowoff = (slq + j2) * PROW + slu * 12 + 4 * p;
                    float b2 = tw2s[s][j2];
                    #pragma unroll
                    for (int j1 = 0; j1 < 6; ++j1) {
                        float4 gq = *(const float4*)&patch[rowoff + j1 * 12];
                        const __half2* h = (const __half2*)&gq;
                        float ww = b2 * tw1s[s][j1];
                        #pragma unroll
                        for (int k = 0; k < 4; ++k) {
                            float2 fv = __half22float2(h[k]);
                            ar[k] = fmaf(ww, fv.x, ar[k]);
                            ai[k] = fmaf(ww, fv.y, ai[k]);
                        }
                    }
                }
                #pragma unroll
                for (int k = 0; k < 4; ++k)
                    out[(4 * p + k) * MS + m] = make_float2(ar[k], ai[k]);
            }
            __syncthreads();
        }
        __syncthreads();   // ns may be 0: still fence before next rep's stage
    }
}

extern "C" void kernel_launch(void* const* d_in, const int* in_sizes, int n_in,
                              void* d_out, int out_size, void* d_ws, size_t ws_size,
                              hipStream_t stream) {
    const float* img_r = (const float*)d_in[0];
    const float* img_i = (const float*)d_in[1];
    const float* sm_r  = (const float*)d_in[2];
    const float* sm_i  = (const float*)d_in[3];
    const float* kt    = (const float*)d_in[4];

    char* base = (char*)d_ws;
    unsigned int* R16  = (unsigned int*)base;                   // 12*320*640*4
    unsigned int* Gpad = (unsigned int*)(base + 9830400);       // 645*645*12*4
    int* cnt           = (int*)(base + 29799600);
    int* offs          = (int*)(base + 29806000);
    int* order         = (int*)(base + 29812400);

    hipMemsetAsync(cnt, 0, NTILES * sizeof(int), stream);
    passA_kernel<<<480, 512, 0, stream>>>(img_r, img_i, sm_r, sm_i, kt, cnt, R16);
    passB1G_kernel<<<GSZ, 512, 0, stream>>>(R16, cnt, offs, Gpad);
    binscatter_kernel<<<400, 256, 0, stream>>>(kt, offs, order);
    interp_tiled_kernel<<<NTILES, 256, 0, stream>>>(kt, Gpad, cnt, offs, order, (float2*)d_out);
}

// Round 7
// 218.715 us; speedup vs baseline: 1.2491x; 1.2491x over previous
//
#include <hip/hip_runtime.h>
#include <hip/hip_fp16.h>
#include <hip/hip_cooperative_groups.h>

namespace cg = cooperative_groups;

#define GSZ 640
#define NIMG 320
#define MS 102400
#define NC 12
#define BETA_F 13.8551004f
#define TWOPI_F 6.2831855f
#define GSC 16777216.0f
#define GSC_INV 5.9604645e-8f

#define TEDGE 16
#define NT1 40
#define NTILES 1600
#define PAT 21
#define PROW 252          // PAT*NC uints per patch row
#define GPAD 645          // 640 + 5 halo (pad coord = true + 2)
#define NSMAX 128
#define SHBYTES 28672

// ---------- Bessel I0 ----------
__device__ __forceinline__ float i0f(float x) {
    float ax = fabsf(x);
    if (ax < 3.75f) {
        float t = ax * (1.0f / 3.75f);
        t *= t;
        return 1.0f + t * (3.5156229f + t * (3.0899424f + t * (1.2067492f +
                     t * (0.2659732f + t * (0.0360768f + t * 0.0045813f)))));
    } else {
        float t = 3.75f / ax;
        float p = 0.39894228f + t * (0.01328592f + t * (0.00225319f + t * (-0.00157565f +
                  t * (0.00916281f + t * (-0.02057706f + t * (0.02635537f +
                  t * (-0.01647633f + t * 0.00392377f)))))));
        return p * __expf(ax) * rsqrtf(ax);
    }
}

__device__ __forceinline__ float kbval(float u) {
    float mm = fabsf(u) * (1.0f / 3.0f);
    float s = 1.0f - mm * mm;
    s = s > 0.0f ? s : 0.0f;
    float v = i0f(BETA_F * sqrtf(s)) * (1.0f / 6.0f);
    return (mm <= 1.0f) ? v : 0.0f;
}

__device__ __forceinline__ int tapbase(float om, float* frac) {
    float t = fmodf((om * 640.0f) / TWOPI_F, 640.0f);
    if (t < 0.0f) t += 640.0f;
    float b = floorf(t);
    *frac = t - b;
    int ib = (int)b;
    if (ib >= GSZ) ib -= GSZ;
    return ib;
}

__device__ __forceinline__ float2 cmul(float2 a, float2 w) {
    return make_float2(a.x * w.x - a.y * w.y, a.x * w.y + a.y * w.x);
}

// ===== wave-level 640-pt FFT (verified R4/R5) =====
__device__ __forceinline__ void wf_init(int lane, float2* t64, float2* t640, int* br) {
    #pragma unroll
    for (int m = 0; m < 6; ++m) {
        int mask = 32 >> m;
        float e = (float)((lane & (mask - 1)) << m);
        float sn, cs;
        __sincosf((-TWOPI_F / 64.0f) * e, &sn, &cs);
        t64[m] = make_float2(cs, sn);
    }
    float sn, cs;
    __sincosf((-TWOPI_F / 640.0f) * (float)lane, &sn, &cs);
    float2 w1 = make_float2(cs, sn);
    t640[0] = make_float2(1.0f, 0.0f);
    #pragma unroll
    for (int k = 1; k < 10; ++k) t640[k] = cmul(t640[k - 1], w1);
    *br = (int)(__brev((unsigned int)lane) >> 26);
}

__device__ __forceinline__ void dft10(const float2* v, float2* y) {
    const float wr5[5] = {1.0f, 0.30901699f, -0.80901699f, -0.80901699f, 0.30901699f};
    const float wi5[5] = {0.0f, -0.95105652f, -0.58778525f, 0.58778525f, 0.95105652f};
    float2 E[5], O[5];
    #pragma unroll
    for (int r = 0; r < 5; ++r) {
        float er = v[0].x, ei = v[0].y;
        float os = v[1].x, oi = v[1].y;
        #pragma unroll
        for (int c = 1; c < 5; ++c) {
            int k = (r * c) % 5;
            er += v[2 * c].x * wr5[k] - v[2 * c].y * wi5[k];
            ei += v[2 * c].x * wi5[k] + v[2 * c].y * wr5[k];
            os += v[2 * c + 1].x * wr5[k] - v[2 * c + 1].y * wi5[k];
            oi += v[2 * c + 1].x * wi5[k] + v[2 * c + 1].y * wr5[k];
        }
        E[r] = make_float2(er, ei);
        O[r] = make_float2(os, oi);
    }
    const float wr10[10] = {1.0f, 0.80901699f, 0.30901699f, -0.30901699f, -0.80901699f,
                            -1.0f, -0.80901699f, -0.30901699f, 0.30901699f, 0.80901699f};
    const float wi10[10] = {0.0f, -0.58778525f, -0.95105652f, -0.95105652f, -0.58778525f,
                            0.0f, 0.58778525f, 0.95105652f, 0.95105652f, 0.58778525f};
    #pragma unroll
    for (int k = 0; k < 10; ++k) {
        int r = k % 5;
        float2 t = cmul(O[r], make_float2(wr10[k], wi10[k]));
        y[k] = make_float2(E[r].x + t.x, E[r].y + t.y);
    }
}

__device__ __forceinline__ void wfft640(float2* v, const float2* t640, const float2* t64,
                                        int lane) {
    float2 y[10];
    dft10(v, y);
    #pragma unroll
    for (int k = 1; k < 10; ++k) y[k] = cmul(y[k], t640[k]);
    #pragma unroll
    for (int m = 0; m < 6; ++m) {
        int mask = 32 >> m;
        bool up = (lane & mask) != 0;
        float2 tw = t64[m];
        #pragma unroll
        for (int k = 0; k < 10; ++k) {
            float2 a = y[k];
            float2 b;
            b.x = __shfl_xor(a.x, mask, 64);
            b.y = __shfl_xor(a.y, mask, 64);
            float2 d = make_float2(b.x - a.x, b.y - a.y);
            float2 cm = cmul(d, tw);
            y[k] = up ? cm : make_float2(a.x + b.x, a.y + b.y);
        }
    }
    #pragma unroll
    for (int k = 0; k < 10; ++k) v[k] = y[k];
}

// ---------- scan: 1600 counts -> exclusive offsets (one block, >=256 thr) ----------
__device__ void scan_inline(const int* __restrict__ cnt, int* __restrict__ offs, int* sp) {
    int t = threadIdx.x;
    int c7[7];
    int psum = 0;
    if (t < 256) {
        #pragma unroll
        for (int k = 0; k < 7; ++k) {
            int i = t * 7 + k;
            int v = (i < NTILES) ? cnt[i] : 0;
            c7[k] = v;
            psum += v;
        }
        sp[t] = psum;
    }
    __syncthreads();
    for (int off = 1; off < 256; off <<= 1) {
        int v = (t >= off && t < 256) ? sp[t - off] : 0;
        __syncthreads();
        if (t < 256) sp[t] += v;
        __syncthreads();
    }
    if (t < 256) {
        int run = (t == 0) ? 0 : sp[t - 1];
        #pragma unroll
        for (int k = 0; k < 7; ++k) {
            int i = t * 7 + k;
            if (i < NTILES) offs[i] = run;
            run += c7[k];
        }
    }
}

// ================= phase bodies (grid-stride; any grid size) =================
__device__ void phase0(const float* img_r, const float* img_i, const float* sm_r,
                       const float* sm_i, const float* kt, int* cnt,
                       unsigned int* R16, char* shraw) {
    unsigned int* Rs = (unsigned int*)shraw;              // [8][640]
    float* apodS = (float*)(shraw + 20480);               // [320]
    int tid = threadIdx.x, lane = tid & 63, wv = tid >> 6;
    int gsz = gridDim.x * 512;
    for (int g = blockIdx.x * 512 + tid; g < MS; g += gsz) {   // bincount
        float f;
        int ibu = tapbase(kt[g], &f);
        int ibq = tapbase(kt[MS + g], &f);
        atomicAdd(&cnt[(ibq >> 4) * NT1 + (ibu >> 4)], 1);
    }
    if (tid < NIMG) {
        int n = tid;
        float s = 0.0f;
        #pragma unroll
        for (int j = -3; j <= 3; ++j)
            s += kbval((float)j) * __cosf((TWOPI_F * (float)j * ((float)n - 160.0f)) / 640.0f);
        apodS[n] = 1.0f / s;
    }
    float2 t64[6], t640[10];
    int br;
    wf_init(lane, t64, t640, &br);
    __syncthreads();                                      // apodS ready
    int nw = gridDim.x * 8;
    for (int id = blockIdx.x * 8 + wv; id < NC * NIMG; id += nw) {
        int c = id / 320, ri = id - 320 * c;
        int h = (ri < 160) ? ri + 160 : ri - 160;
        const float* ir = img_r + h * NIMG;
        const float* ii = img_i + h * NIMG;
        const float* smr = sm_r + (c * NIMG + h) * NIMG;
        const float* smi = sm_i + (c * NIMG + h) * NIMG;
        float ah = apodS[h] * (GSC / 640.0f);
        auto ld = [&](int wc) {
            float xr = ir[wc], xi = ii[wc];
            float sr = smr[wc], si = smi[wc];
            float sc = ah * apodS[wc];
            return make_float2((xr * sr - xi * si) * sc, (xr * si + xi * sr) * sc);
        };
        const float2 z2 = make_float2(0.0f, 0.0f);
        float2 v[10];
        v[0] = ld(lane + 160);
        v[1] = ld(lane + 224);
        { float2 tv = ld((lane < 32) ? lane + 288 : 0); v[2] = (lane < 32) ? tv : z2; }
        v[3] = z2; v[4] = z2; v[5] = z2; v[6] = z2;
        { float2 tv = ld((lane >= 32) ? lane - 32 : 0); v[7] = (lane >= 32) ? tv : z2; }
        v[8] = ld(lane + 32);
        v[9] = ld(lane + 96);
        wfft640(v, t640, t64, lane);
        unsigned int* rs = Rs + wv * GSZ;                 // wave-private (in-order DS)
        #pragma unroll
        for (int k = 0; k < 10; ++k) {
            __half2 hv = __float22half2_rn(v[k]);
            rs[10 * br + k] = *(const unsigned int*)&hv;
        }
        unsigned int* outp = R16 + (c * 320 + ri) * GSZ;
        #pragma unroll
        for (int j = 0; j < 10; ++j)
            outp[lane + 64 * j] = rs[lane + 64 * j];      // coalesced row write
    }
}

__device__ void phase1(const unsigned int* R16, const int* cnt, int* offs,
                       unsigned int* Gpad, char* shraw) {
    int tid = threadIdx.x, lane = tid & 63, wv = tid >> 6;
    if (blockIdx.x == 0) scan_inline(cnt, offs, (int*)(shraw + 20480));
    unsigned int* rsw = (unsigned int*)shraw + wv * GSZ;  // wave-private row buf
    float2 t64[6], t640[10];
    int br;
    wf_init(lane, t64, t640, &br);
    const float2 z2 = make_float2(0.0f, 0.0f);
    int nw = gridDim.x * 8;
    for (int i = blockIdx.x * 8 + wv; i < NC * GSZ; i += nw) {
        int c = i / GSZ, q = i - c * GSZ;
        const unsigned int* col = R16 + (size_t)c * 320 * GSZ + q;
        auto ld = [&](int t) {
            unsigned int raw = col[(size_t)t * GSZ];
            return __half22float2(*(const __half2*)&raw);
        };
        float2 v[10];
        v[0] = ld(lane);
        v[1] = ld(lane + 64);
        { float2 tv = ld(lane + 128);
          v[2] = (lane < 32) ? tv : z2;
          v[7] = (lane < 32) ? z2 : tv; }
        v[3] = z2; v[4] = z2; v[5] = z2; v[6] = z2;
        v[8] = ld(lane + 192);
        v[9] = ld(lane + 256);
        wfft640(v, t640, t64, lane);
        #pragma unroll
        for (int k = 0; k < 10; ++k) {
            __half2 hv = __float22half2_rn(v[k]);
            rsw[10 * br + k] = *(const unsigned int*)&hv;
        }
        unsigned int* rowp = Gpad + ((size_t)c * GPAD + (q + 2)) * GPAD;
        for (int idx = lane; idx < GPAD; idx += 64) {
            int u = (idx < 2) ? idx + 638 : (idx < 642) ? idx - 2 : idx - 642;
            rowp[idx] = rsw[u];
        }
        int qp2 = (q < 3) ? q + 642 : ((q >= 638) ? q - 638 : -1);
        if (qp2 >= 0) {                                   // q-halo duplicate row
            unsigned int* rowp2 = Gpad + ((size_t)c * GPAD + qp2) * GPAD;
            for (int idx = lane; idx < GPAD; idx += 64) {
                int u = (idx < 2) ? idx + 638 : (idx < 642) ? idx - 2 : idx - 642;
                rowp2[idx] = rsw[u];
            }
        }
    }
}

__device__ void phase2(const float* kt, int* offs, int* order) {
    int gsz = gridDim.x * blockDim.x;
    for (int m = blockIdx.x * blockDim.x + threadIdx.x; m < MS; m += gsz) {
        float f;
        int ibu = tapbase(kt[m], &f);
        int ibq = tapbase(kt[MS + m], &f);
        int pos = atomicAdd(&offs[(ibq >> 4) * NT1 + (ibu >> 4)], 1);
        order[pos] = m;
    }
}

__device__ void phase3(const float* kt, const unsigned int* Gpad, const int* cnt,
                       const int* offs, const int* order, float2* out, char* shraw) {
    unsigned int* patch = (unsigned int*)shraw;           // 21168B
    float (*tw1s)[6] = (float(*)[6])(shraw + 21168);      // 3072B
    float (*tw2s)[6] = (float(*)[6])(shraw + 24240);      // 3072B
    int* tslm = (int*)(shraw + 27312);                    // 512B
    int tid = threadIdx.x;
    for (int tile = blockIdx.x; tile < NTILES; tile += gridDim.x) {
        int TQ = tile / NT1, TU = tile - TQ * NT1;
        {   // stage patch from 12 coil planes (84B coalesced runs), interleave in LDS
            int base0 = TQ * TEDGE * GPAD + TU * TEDGE;
            for (int i = tid; i < NC * PAT * PAT; i += 512) {
                int c = i / (PAT * PAT);
                int rem = i - c * (PAT * PAT);
                int r = rem / PAT, u = rem - r * PAT;
                patch[r * PROW + u * NC + c] =
                    Gpad[(size_t)c * (GPAD * GPAD) + base0 + r * GPAD + u];
            }
        }
        int end = offs[tile], ns = cnt[tile], start = end - ns;
        for (int s0 = 0; s0 < ns; s0 += NSMAX) {
            int nss = min(NSMAX, ns - s0);
            if (tid < nss) {
                int m = order[start + s0 + tid];
                float fu, fq;
                int ibu = tapbase(kt[m], &fu);
                int ibq = tapbase(kt[MS + m], &fq);
                #pragma unroll
                for (int j = 0; j < 6; ++j) {
                    tw1s[tid][j] = kbval(fu + (float)(2 - j));
                    tw2s[tid][j] = kbval(fq + (float)(2 - j)) * GSC_INV;
                }
                tslm[tid] = (m << 8) | ((ibu & 15) << 4) | (ibq & 15);
            }
            __syncthreads();                              // patch + taps ready
            for (int it = tid; it < 3 * nss; it += 512) {
                int s = it / 3;
                int p = it - 3 * s;
                int pk = tslm[s];
                int slq = pk & 15, slu = (pk >> 4) & 15, m = pk >> 8;
                float ar[4] = {0.f, 0.f, 0.f, 0.f}, ai[4] = {0.f, 0.f, 0.f, 0.f};
                #pragma unroll
                for (int j2 = 0; j2 < 6; ++j2) {
                    int rowoff = (slq + j2) * PROW + slu * NC + 4 * p;
                    float b2 = tw2s[s][j2];
                    #pragma unroll
                    for (int j1 = 0; j1 < 6; ++j1) {
                        float4 gq = *(const float4*)&patch[rowoff + j1 * NC];
                        const __half2* h = (const __half2*)&gq;
                        float ww = b2 * tw1s[s][j1];
                        #pragma unroll
                        for (int k = 0; k < 4; ++k) {
                            float2 fv = __half22float2(h[k]);
                            ar[k] = fmaf(ww, fv.x, ar[k]);
                            ai[k] = fmaf(ww, fv.y, ai[k]);
                        }
                    }
                }
                #pragma unroll
                for (int k = 0; k < 4; ++k)
                    out[(4 * p + k) * MS + m] = make_float2(ar[k], ai[k]);
            }
            __syncthreads();                              // before next chunk taps
        }
        __syncthreads();                                  // before next tile stage
    }
}

// ================= fused cooperative kernel =================
__global__ __launch_bounds__(512)
void fused_kernel(const float* img_r, const float* img_i, const float* sm_r,
                  const float* sm_i, const float* kt,
                  unsigned int* R16, unsigned int* Gpad,
                  int* cnt, int* offs, int* order, float2* out) {
    cg::grid_group grid = cg::this_grid();
    __shared__ __align__(16) char shraw[SHBYTES];
    phase0(img_r, img_i, sm_r, sm_i, kt, cnt, R16, shraw);
    __threadfence();
    grid.sync();
    __threadfence();
    phase1(R16, cnt, offs, Gpad, shraw);
    __threadfence();
    grid.sync();
    __threadfence();
    phase2(kt, offs, order);
    __threadfence();
    grid.sync();
    __threadfence();
    phase3(kt, Gpad, cnt, offs, order, out, shraw);
}

// ================= fallback wrappers (identical phase code) =================
__global__ __launch_bounds__(512)
void kA(const float* img_r, const float* img_i, const float* sm_r, const float* sm_i,
        const float* kt, int* cnt, unsigned int* R16) {
    __shared__ __align__(16) char shraw[SHBYTES];
    phase0(img_r, img_i, sm_r, sm_i, kt, cnt, R16, shraw);
}
__global__ __launch_bounds__(512)
void kB(const unsigned int* R16, const int* cnt, int* offs, unsigned int* Gpad) {
    __shared__ __align__(16) char shraw[SHBYTES];
    phase1(R16, cnt, offs, Gpad, shraw);
}
__global__ __launch_bounds__(512)
void kC(const float* kt, int* offs, int* order) {
    phase2(kt, offs, order);
}
__global__ __launch_bounds__(512)
void kD(const float* kt, const unsigned int* Gpad, const int* cnt, const int* offs,
        const int* order, float2* out) {
    __shared__ __align__(16) char shraw[SHBYTES];
    phase3(kt, Gpad, cnt, offs, order, out, shraw);
}

extern "C" void kernel_launch(void* const* d_in, const int* in_sizes, int n_in,
                              void* d_out, int out_size, void* d_ws, size_t ws_size,
                              hipStream_t stream) {
    const float* img_r = (const float*)d_in[0];
    const float* img_i = (const float*)d_in[1];
    const float* sm_r  = (const float*)d_in[2];
    const float* sm_i  = (const float*)d_in[3];
    const float* kt    = (const float*)d_in[4];

    char* base = (char*)d_ws;
    unsigned int* R16  = (unsigned int*)base;                   // 12*320*640*4 = 9.83MB
    unsigned int* Gpad = (unsigned int*)(base + 9830400);       // 12*645*645*4 = 19.97MB
    int* cnt           = (int*)(base + 29799600);
    int* offs          = (int*)(base + 29806000);
    int* order         = (int*)(base + 29812400);
    float2* outp       = (float2*)d_out;

    hipMemsetAsync(cnt, 0, NTILES * sizeof(int), stream);

    // Real co-residency from the driver (pure query; capture-safe), then checked
    // cooperative launch with sequential-kernel fallback (R6 lesson: the 512-block
    // launch was silently rejected -> all-zero output).
    int occ = 0;
    hipError_t oe = hipOccupancyMaxActiveBlocksPerMultiprocessor(&occ, fused_kernel, 512, 0);
    int nblk = (oe == hipSuccess && occ > 0) ? occ * 256 : 0;
    if (nblk > 512) nblk = 512;
    bool done = false;
    if (nblk >= 8) {
        void* kargs[] = {(void*)&img_r, (void*)&img_i, (void*)&sm_r, (void*)&sm_i,
                         (void*)&kt, (void*)&R16, (void*)&Gpad, (void*)&cnt,
                         (void*)&offs, (void*)&order, (void*)&outp};
        hipError_t st = hipLaunchCooperativeKernel((void*)fused_kernel, dim3(nblk),
                                                   dim3(512), kargs, 0, stream);
        if (st == hipSuccess) done = true;
        else (void)hipGetLastError();                     // clear sticky error
    }
    if (!done) {
        kA<<<480, 512, 0, stream>>>(img_r, img_i, sm_r, sm_i, kt, cnt, R16);
        kB<<<512, 512, 0, stream>>>(R16, cnt, offs, Gpad);
        kC<<<200, 512, 0, stream>>>(kt, offs, order);
        kD<<<512, 512, 0, stream>>>(kt, Gpad, cnt, offs, order, outp);
    }
}